// Round 32
// baseline (121.600 us; speedup 1.0000x reference)
//
#include <hip/hip_runtime.h>
#include <math.h>

// Problem constants
#define B_  8
#define N_  196
#define C_  12
#define D_  768
#define H_  12
#define R_  (B_*N_*C_)      // 18816 rows
#define KDIM 768
#define NQKV_PAD 768        // 720 real qkv cols padded to 768

typedef _Float16 f16x8 __attribute__((ext_vector_type(8)));   // 8 f16 = 4 VGPR
typedef _Float16 f16x4 __attribute__((ext_vector_type(4)));   // 4 f16 = 2 VGPR
typedef __fp16 fp16x2 __attribute__((ext_vector_type(2)));    // cvt_pkrtz return type
typedef __attribute__((ext_vector_type(4))) float f32x4;

__device__ inline unsigned short f2h(float f) {
    union { _Float16 h; unsigned short u; } v; v.h = (_Float16)f; return v.u;
}
__device__ inline float h2f(unsigned short u) {
    union { unsigned short u; _Float16 h; } v; v.u = u; return (float)v.h;
}
// single-instruction packed f32x2 -> f16x2 (RTZ)
__device__ inline unsigned pk2u(float a, float b) {
    union { fp16x2 h; unsigned u; } v;
    v.h = __builtin_amdgcn_cvt_pkrtz(a, b);
    return v.u;
}
// scale both f16 halves of a packed word
__device__ inline unsigned scale2(unsigned u, float s) {
    return pk2u(h2f((unsigned short)(u & 0xffff)) * s,
                h2f((unsigned short)(u >> 16)) * s);
}

// ---------------------------------------------------------------------------
// Weights-only conversion (r27-verified).
// ---------------------------------------------------------------------------
__global__ __launch_bounds__(256) void convert_weights(
    const float* __restrict__ wc, const float* __restrict__ ws,
    const float* __restrict__ wp,
    unsigned short* __restrict__ wqkv_h, unsigned short* __restrict__ wp_h)
{
    int i = (blockIdx.x * 256 + threadIdx.x) * 4;
    float4 v; unsigned short* dh; int off;
    if (i < 768 * 768) {
        off = i;
        const int r = off / 768, k = off % 768;
        v = make_float4(0.f, 0.f, 0.f, 0.f);
        if (r < 144)      v = *reinterpret_cast<const float4*>(wc + r * 768 + k);
        else if (r < 720) v = *reinterpret_cast<const float4*>(ws + (r - 144) * 768 + k);
        dh = wqkv_h;
    } else {
        off = i - 768 * 768;
        if (off >= 768 * 768) return;
        v = *reinterpret_cast<const float4*>(wp + off);
        dh = wp_h;
    }
    uint2 h;
    h.x = pk2u(v.x, v.y);
    h.y = pk2u(v.z, v.w);
    *reinterpret_cast<uint2*>(dh + off) = h;
}

#define BM 128
#define BN 128
#define BK 64

__device__ inline void gload16(const unsigned short* src, void* ldsbase) {
    __builtin_amdgcn_global_load_lds(
        (const __attribute__((address_space(1))) unsigned int*)src,
        (__attribute__((address_space(3))) unsigned int*)ldsbase, 16, 0, 0);
}

// ---------------------------------------------------------------------------
// FUSED qkv GEMM (r30/r31-verified). Unchanged.
// ---------------------------------------------------------------------------
__global__ __launch_bounds__(512, 2) void gemm_qkv_fused(
    const float* __restrict__ Af, const unsigned short* __restrict__ Bh,
    unsigned short* __restrict__ outh, int M, int Nt, int K, int ntiles)
{
    __shared__ unsigned short sA[2][BM][BK];   // 2 x 16 KB
    __shared__ unsigned short sB[2][BN][BK];   // 2 x 16 KB

    const int nwg = gridDim.x;
    const int bid = blockIdx.x;
    const int xcd = bid & 7, slot = bid >> 3;
    const int q = nwg >> 3, r = nwg & 7;
    const int wg = (xcd < r ? xcd * (q + 1) : r * (q + 1) + (xcd - r) * q) + slot;
    const int mt = wg / ntiles, nt = wg - mt * ntiles;   // nt fast: A-panel reuse
    const int m0 = mt * BM, n0 = nt * BN;

    const int tid = threadIdx.x;
    const int w = tid >> 6, l = tid & 63;
    const int fl = l & 15, g = l >> 4;
    const int wr = (w >> 2) * 64;              // wave row base
    const int wc = (w & 3) * 32;               // wave col base

    f32x4 acc[4][2];
    #pragma unroll
    for (int i = 0; i < 4; ++i)
        #pragma unroll
        for (int j = 0; j < 2; ++j)
            acc[i][j] = (f32x4){0.f, 0.f, 0.f, 0.f};

    const int srow = w * 16 + (l >> 3);
    const int scol = ((l & 7) ^ (l >> 3)) * 8;

    float4 a0, a1, a2, a3;                     // A f32 staging regs (one k-tile)

#define LOADA(kk) {                                                                         \
    const float* paf = Af + (size_t)(m0 + srow) * K + (kk) + scol;                          \
    a0 = *reinterpret_cast<const float4*>(paf);                                             \
    a1 = *reinterpret_cast<const float4*>(paf + 4);                                         \
    a2 = *reinterpret_cast<const float4*>(paf + 8 * K);                                     \
    a3 = *reinterpret_cast<const float4*>(paf + 8 * K + 4); }

#define WRITEA(buf) {                                                                       \
    char* da = (char*)sA + (buf) * 16384 + w * 2048 + l * 16;                               \
    uint4 v0 = { pk2u(a0.x,a0.y), pk2u(a0.z,a0.w), pk2u(a1.x,a1.y), pk2u(a1.z,a1.w) };      \
    uint4 v1 = { pk2u(a2.x,a2.y), pk2u(a2.z,a2.w), pk2u(a3.x,a3.y), pk2u(a3.z,a3.w) };      \
    *reinterpret_cast<uint4*>(da) = v0;                                                     \
    *reinterpret_cast<uint4*>(da + 1024) = v1; }

#define STAGEB(buf, kk) {                                                                   \
    const unsigned short* pb = Bh + (size_t)(n0 + srow) * K + (kk) + scol;                  \
    char* db = (char*)sB + (buf) * 16384 + w * 2048;                                        \
    gload16(pb,          db);                                                               \
    gload16(pb + 8 * K,  db + 1024); }

    // prologue
    LOADA(0);                                  // 4 vm
    STAGEB(0, 0);                              // 2 vm
    asm volatile("s_waitcnt vmcnt(2)" ::: "memory");    // A(0) regs done (B(0) may fly)
    WRITEA(0);
    LOADA(BK);                                 // aregs(1), 4 vm
    asm volatile("s_waitcnt lgkmcnt(0)" ::: "memory");  // A(0) writes done

    const int KT = K / BK;             // 12
    int cur = 0;
    for (int t = 0; t < KT; ++t) {
        if (t + 1 < KT) {
            STAGEB(cur ^ 1, (t + 1) * BK);                     // 2 vm
            asm volatile("s_waitcnt vmcnt(2)" ::: "memory");   // B(t)+aregs(t+1) done
        } else {
            asm volatile("s_waitcnt vmcnt(0)" ::: "memory");
        }
        asm volatile("s_barrier" ::: "memory");                // buf[cur] ready

        // ---- ks = 0 ----
        {
            const int rcol = (g ^ (fl & 7)) * 8;
            f16x8 ah[4];
            #pragma unroll
            for (int fm = 0; fm < 4; ++fm)
                ah[fm] = *reinterpret_cast<const f16x8*>(&sA[cur][wr + fm * 16 + fl][rcol]);
            __builtin_amdgcn_s_setprio(1);
            #pragma unroll
            for (int fn = 0; fn < 2; ++fn) {
                const f16x8 bf = *reinterpret_cast<const f16x8*>(&sB[cur][wc + fn * 16 + fl][rcol]);
                #pragma unroll
                for (int fm = 0; fm < 4; ++fm)
                    acc[fm][fn] = __builtin_amdgcn_mfma_f32_16x16x32_f16(ah[fm], bf, acc[fm][fn], 0, 0, 0);
            }
            __builtin_amdgcn_s_setprio(0);
        }
        // A-path work under MFMA cover (published by end-of-iter lgkm+barrier)
        if (t + 1 < KT) WRITEA(cur ^ 1);
        if (t + 2 < KT) LOADA((t + 2) * BK);
        // ---- ks = 1 ----
        {
            const int rcol = ((4 + g) ^ (fl & 7)) * 8;
            f16x8 ah[4];
            #pragma unroll
            for (int fm = 0; fm < 4; ++fm)
                ah[fm] = *reinterpret_cast<const f16x8*>(&sA[cur][wr + fm * 16 + fl][rcol]);
            __builtin_amdgcn_s_setprio(1);
            #pragma unroll
            for (int fn = 0; fn < 2; ++fn) {
                const f16x8 bf = *reinterpret_cast<const f16x8*>(&sB[cur][wc + fn * 16 + fl][rcol]);
                #pragma unroll
                for (int fm = 0; fm < 4; ++fm)
                    acc[fm][fn] = __builtin_amdgcn_mfma_f32_16x16x32_f16(ah[fm], bf, acc[fm][fn], 0, 0, 0);
            }
            __builtin_amdgcn_s_setprio(0);
        }
        asm volatile("s_waitcnt lgkmcnt(0)" ::: "memory");  // publish A(t+1) writes
        asm volatile("s_barrier" ::: "memory");             // WAR fence
        cur ^= 1;
    }
#undef LOADA
#undef WRITEA
#undef STAGEB

    const int rg = g * 4;
    #pragma unroll
    for (int fm = 0; fm < 4; ++fm)
        #pragma unroll
        for (int fn = 0; fn < 2; ++fn) {
            const int row = m0 + wr + fm * 16 + rg;
            const int col = n0 + wc + fn * 16 + fl;
            #pragma unroll
            for (int rr = 0; rr < 4; ++rr)
                outh[(size_t)(row + rr) * Nt + col] = f2h(acc[fm][fn][rr]);
        }
}

// ---------------------------------------------------------------------------
// Proj GEMM. THIS ROUND: BM=128, BN=64 -> LDS 48KB -> 3 blocks/CU (24 waves,
// was 16). 8 waves, wave tile 32x32 (acc[2][2]); staging 3 gloads/step
// (A 2, B 1), counted vmcnt(3); same XOR-swizzle involution (B rows
// w*8+(l>>3): row&7 == l>>3). Grid 147 x 12.
// ---------------------------------------------------------------------------
__global__ __launch_bounds__(512, 2) void gemm_f16(
    const unsigned short* __restrict__ Ah, const unsigned short* __restrict__ Bh,
    const float* __restrict__ bias,
    float* __restrict__ outp, int M, int Nt, int K, int ntiles)
{
    __shared__ unsigned short sA[2][128][64];  // 32 KB
    __shared__ unsigned short sB[2][64][64];   // 16 KB

    const int nwg = gridDim.x;
    const int bid = blockIdx.x;
    const int xcd = bid & 7, slot = bid >> 3;
    const int q = nwg >> 3, r = nwg & 7;
    const int wg = (xcd < r ? xcd * (q + 1) : r * (q + 1) + (xcd - r) * q) + slot;
    const int mt = wg / ntiles, nt = wg - mt * ntiles;   // nt fast: A-panel reuse
    const int m0 = mt * 128, n0 = nt * 64;

    const int tid = threadIdx.x;
    const int w = tid >> 6, l = tid & 63;
    const int fl = l & 15, g = l >> 4;
    const int wr = (w >> 1) * 32;              // wave row base (0,32,64,96)
    const int wc = (w & 1) * 32;               // wave col base (0,32)

    f32x4 acc[2][2];
    #pragma unroll
    for (int i = 0; i < 2; ++i)
        #pragma unroll
        for (int j = 0; j < 2; ++j)
            acc[i][j] = (f32x4){0.f, 0.f, 0.f, 0.f};

    const int srowA = w * 16 + (l >> 3);
    const int srowB = w * 8 + (l >> 3);
    const int scol = ((l & 7) ^ (l >> 3)) * 8;

#define STAGE(buf, kk) {                                                                    \
    const unsigned short* pa = Ah + (size_t)(m0 + srowA) * K + (kk) + scol;                 \
    const unsigned short* pb = Bh + (size_t)(n0 + srowB) * K + (kk) + scol;                 \
    char* da = (char*)sA + (buf) * 16384 + w * 2048;                                        \
    char* db = (char*)sB + (buf) * 8192 + w * 1024;                                         \
    gload16(pa,          da);                                                               \
    gload16(pa + 8 * K,  da + 1024);                                                        \
    gload16(pb,          db); }

    STAGE(0, 0);                       // 3 loads in flight

    const int KT = K / BK;             // 12
    int cur = 0;
    for (int t = 0; t < KT; ++t) {
        if (t + 1 < KT) {
            STAGE(cur ^ 1, (t + 1) * BK);                      // +3 -> 6 in flight
            asm volatile("s_waitcnt vmcnt(3)" ::: "memory");   // drain tile t only
        } else {
            asm volatile("s_waitcnt vmcnt(0)" ::: "memory");
        }
        asm volatile("s_barrier" ::: "memory");                // tile t visible

        #pragma unroll
        for (int ks = 0; ks < 2; ++ks) {
            const int rcol = ((ks * 4 + g) ^ (fl & 7)) * 8;
            f16x8 ah[2];
            #pragma unroll
            for (int fm = 0; fm < 2; ++fm)
                ah[fm] = *reinterpret_cast<const f16x8*>(&sA[cur][wr + fm * 16 + fl][rcol]);
            __builtin_amdgcn_s_setprio(1);
            #pragma unroll
            for (int fn = 0; fn < 2; ++fn) {
                const f16x8 bf = *reinterpret_cast<const f16x8*>(&sB[cur][wc + fn * 16 + fl][rcol]);
                #pragma unroll
                for (int fm = 0; fm < 2; ++fm)
                    acc[fm][fn] = __builtin_amdgcn_mfma_f32_16x16x32_f16(ah[fm], bf, acc[fm][fn], 0, 0, 0);
            }
            __builtin_amdgcn_s_setprio(0);
        }
        asm volatile("s_barrier" ::: "memory");   // WAR fence before restaging [cur]
        cur ^= 1;
    }
#undef STAGE

    const int rg = g * 4;
    #pragma unroll
    for (int fm = 0; fm < 2; ++fm)
        #pragma unroll
        for (int fn = 0; fn < 2; ++fn) {
            const int row = m0 + wr + fm * 16 + rg;
            const int col = n0 + wc + fn * 16 + fl;
            const float bv = bias[col];
            #pragma unroll
            for (int rr = 0; rr < 4; ++rr)
                outp[(size_t)(row + rr) * Nt + col] = acc[fm][fn][rr] + bv;
        }
}

// ---------------------------------------------------------------------------
// Channel attention -> xc ONLY (r31-verified). Unchanged.
// ---------------------------------------------------------------------------
__global__ __launch_bounds__(256) void chan_attn_xc(
    const unsigned short* __restrict__ qkv,
    unsigned short* __restrict__ xc)
{
    const int sub = threadIdx.x >> 6;
    const int t = threadIdx.x & 63;
    const int flat = blockIdx.x * 4 + sub;     // (b*12+h)*196 + n
    const int n = flat % 196;
    const int h = (flat / 196) % 12;
    const int b = flat / 2352;

    __shared__ float sQ[4][12][4], sK[4][12][4], sV[4][12][4];

    if (t < 36) {                              // (c, s) pairs: 12 x 3
        const int cc = t / 3, s = t % 3;
        const unsigned short* p =
            qkv + (size_t)((b * N_ + n) * 12 + cc) * NQKV_PAD + s * 48 + h * 4;
        const ushort4 v4 = *reinterpret_cast<const ushort4*>(p);
        float* dst = (s == 0) ? &sQ[sub][cc][0] : (s == 1) ? &sK[sub][cc][0] : &sV[sub][cc][0];
        dst[0] = h2f(v4.x); dst[1] = h2f(v4.y); dst[2] = h2f(v4.z); dst[3] = h2f(v4.w);
    }
    __syncthreads();

    if (t < 12) {
        const int c = t;
        float s[12];
        float m = -INFINITY;
        #pragma unroll
        for (int c2 = 0; c2 < 12; ++c2) {
            float d = 0.f;
            #pragma unroll
            for (int e = 0; e < 4; ++e) d += sQ[sub][c][e] * sK[sub][c2][e];
            s[c2] = d * 0.5f;
            m = fmaxf(m, s[c2]);
        }
        float lsum = 0.f;
        #pragma unroll
        for (int c2 = 0; c2 < 12; ++c2) { s[c2] = __expf(s[c2] - m); lsum += s[c2]; }
        const float inv = 1.f / lsum;
        float xcv[4];
        #pragma unroll
        for (int i = 0; i < 4; ++i) {
            float a = 0.f;
            #pragma unroll
            for (int c2 = 0; c2 < 12; ++c2) a += s[c2] * sV[sub][c2][i];
            xcv[i] = a * inv;
        }
        uint2 o;
        o.x = pk2u(xcv[0], xcv[1]);
        o.y = pk2u(xcv[2], xcv[3]);
        *reinterpret_cast<uint2*>(xc + (size_t)flat * 48 + c * 4) = o;
    }
}

// ---------------------------------------------------------------------------
// MFMA spatial attention + fused combine (r31-verified). THIS ROUND:
// xc prefetch hoisted before the ch-loop (hides L2 latency under compute).
// ---------------------------------------------------------------------------
__global__ __launch_bounds__(256) void spatial_attn_mfma(
    const unsigned short* __restrict__ qkv,
    const unsigned short* __restrict__ xc,
    unsigned short* __restrict__ y)
{
    __shared__ unsigned short Kl[224][24];
    __shared__ unsigned short Ql[208][24];
    __shared__ unsigned short Vt[16][236];

    const int bid2 = blockIdx.x;               // 2304 = 1152 x 2
    const int half = bid2 & 1;
    const int bid = bid2 >> 1;
    const int c = bid % 12;
    const int h = (bid / 12) % 12;
    const int b = bid / 144;
    const int tid = threadIdx.x;
    const int w = tid >> 6, l = tid & 63;
    const int fl = l & 15, g = l >> 4;
    const int qbase = half * 7;
    const int ntl = 7 - half;

    const float qs = 0.25f * 1.4426950408889634f;
    for (int idx = tid; idx < N_ * 2; idx += 256) {
        const int n = idx >> 1, eh = (idx & 1) * 8;   // 8 f16 per load
        const unsigned short* base =
            qkv + (size_t)((b * N_ + n) * 12 + c) * NQKV_PAD + 144 + h * 16 + eh;
        const uint4 q4 = *reinterpret_cast<const uint4*>(base);
        const uint4 k4 = *reinterpret_cast<const uint4*>(base + 192);
        const uint4 v4 = *reinterpret_cast<const uint4*>(base + 384);
        uint4 qsc;
        qsc.x = scale2(q4.x, qs); qsc.y = scale2(q4.y, qs);
        qsc.z = scale2(q4.z, qs); qsc.w = scale2(q4.w, qs);
        *reinterpret_cast<uint4*>(&Ql[n][eh]) = qsc;
        *reinterpret_cast<uint4*>(&Kl[n][eh]) = k4;
        Vt[eh + 0][n] = (unsigned short)(v4.x & 0xffff);
        Vt[eh + 1][n] = (unsigned short)(v4.x >> 16);
        Vt[eh + 2][n] = (unsigned short)(v4.y & 0xffff);
        Vt[eh + 3][n] = (unsigned short)(v4.y >> 16);
        Vt[eh + 4][n] = (unsigned short)(v4.z & 0xffff);
        Vt[eh + 5][n] = (unsigned short)(v4.z >> 16);
        Vt[eh + 6][n] = (unsigned short)(v4.w & 0xffff);
        Vt[eh + 7][n] = (unsigned short)(v4.w >> 16);
    }
    for (int idx = tid; idx < 16 * 28; idx += 256) {
        const int d = idx / 28, n = 196 + idx % 28;
        Vt[d][n] = 0;
    }
    __syncthreads();

    f32x4 accO[2];
    float lsum[2];
    #pragma unroll
    for (int j = 0; j < 2; ++j) {
        accO[j] = (f32x4){0.f, 0.f, 0.f, 0.f};
        lsum[j] = 0.f;
    }
    const f32x4 zf = (f32x4){0.f, 0.f, 0.f, 0.f};

    f16x4 Bq[2];
    float xv[2][4];                            // hoisted xc prefetch
    #pragma unroll
    for (int j = 0; j < 2; ++j) {
        const int qtl = w + 4 * j;
        const int qt = (qtl < ntl) ? (qbase + qtl) : 12;
        Bq[j] = *reinterpret_cast<const f16x4*>(&Ql[qt * 16 + fl][4 * g]);
        int n = qt * 16 + fl; if (n > 195) n = 195;
        const ushort4 xc4 = *reinterpret_cast<const ushort4*>(
            xc + (size_t)((b * 12 + h) * 196 + n) * 48 + c * 4);
        xv[j][0] = h2f(xc4.x); xv[j][1] = h2f(xc4.y);
        xv[j][2] = h2f(xc4.z); xv[j][3] = h2f(xc4.w);
    }

    for (int ch = 0; ch < 7; ++ch) {
        const int kb0 = ch * 32;
        const f16x4 Ak0 = *reinterpret_cast<const f16x4*>(&Kl[kb0 + fl][4 * g]);
        const f16x4 Ak1 = *reinterpret_cast<const f16x4*>(&Kl[kb0 + 16 + fl][4 * g]);
        const f16x4 Av0 = *reinterpret_cast<const f16x4*>(&Vt[fl][kb0 + 4 * g]);
        const f16x4 Av1 = *reinterpret_cast<const f16x4*>(&Vt[fl][kb0 + 16 + 4 * g]);

        #pragma unroll
        for (int j = 0; j < 2; ++j) {
            if (w + 4 * j >= ntl) continue;

            __builtin_amdgcn_s_setprio(1);
            f32x4 T0 = __builtin_amdgcn_mfma_f32_16x16x16f16(Ak0, Bq[j], zf, 0, 0, 0);
            f32x4 T1 = __builtin_amdgcn_mfma_f32_16x16x16f16(Ak1, Bq[j], zf, 0, 0, 0);
            __builtin_amdgcn_s_setprio(0);

            float s0 = T0[0], s1 = T0[1], s2 = T0[2], s3 = T0[3];
            float s4 = T1[0], s5 = T1[1], s6 = T1[2], s7 = T1[3];
            if (ch == 6) {
                const int kg = kb0 + 4 * g;
                if (kg + 0 >= 196) s0 = -1e30f;
                if (kg + 1 >= 196) s1 = -1e30f;
                if (kg + 2 >= 196) s2 = -1e30f;
                if (kg + 3 >= 196) s3 = -1e30f;
                s4 = -1e30f; s5 = -1e30f; s6 = -1e30f; s7 = -1e30f;
            }
            const float p0 = exp2f(s0), p1 = exp2f(s1);
            const float p2 = exp2f(s2), p3 = exp2f(s3);
            const float p4 = exp2f(s4), p5 = exp2f(s5);
            const float p6 = exp2f(s6), p7 = exp2f(s7);
            lsum[j] += ((p0 + p1) + (p2 + p3)) + ((p4 + p5) + (p6 + p7));

            union { unsigned u[2]; f16x4 v; } pa, pb;
            pa.u[0] = pk2u(p0, p1); pa.u[1] = pk2u(p2, p3);
            pb.u[0] = pk2u(p4, p5); pb.u[1] = pk2u(p6, p7);

            __builtin_amdgcn_s_setprio(1);
            accO[j] = __builtin_amdgcn_mfma_f32_16x16x16f16(Av0, pa.v, accO[j], 0, 0, 0);
            accO[j] = __builtin_amdgcn_mfma_f32_16x16x16f16(Av1, pb.v, accO[j], 0, 0, 0);
            __builtin_amdgcn_s_setprio(0);
        }
    }

    #pragma unroll
    for (int j = 0; j < 2; ++j) {
        const int qtl = w + 4 * j;
        if (qtl >= ntl) continue;
        const int qt = qbase + qtl;
        float ls = lsum[j];
        ls += __shfl_xor(ls, 16);
        ls += __shfl_xor(ls, 32);
        const int n = qt * 16 + fl;
        if (n < 196) {
            const float inv = 1.f / ls;
            const float o0 = accO[j][0] * inv, o1 = accO[j][1] * inv;
            const float o2 = accO[j][2] * inv, o3 = accO[j][3] * inv;
            const float x0 = xv[j][0], x1 = xv[j][1];
            const float x2 = xv[j][2], x3 = xv[j][3];
            unsigned short* yrow =
                y + ((size_t)(b * N_ + n) * 12 + h) * (size_t)D_ + c * 64 + 4 * g;
            uint2 o;
            o.x = pk2u(x0 * o0, x0 * o1); o.y = pk2u(x0 * o2, x0 * o3);
            *reinterpret_cast<uint2*>(yrow) = o;
            o.x = pk2u(x1 * o0, x1 * o1); o.y = pk2u(x1 * o2, x1 * o3);
            *reinterpret_cast<uint2*>(yrow + 16) = o;
            o.x = pk2u(x2 * o0, x2 * o1); o.y = pk2u(x2 * o2, x2 * o3);
            *reinterpret_cast<uint2*>(yrow + 32) = o;
            o.x = pk2u(x3 * o0, x3 * o1); o.y = pk2u(x3 * o2, x3 * o3);
            *reinterpret_cast<uint2*>(yrow + 48) = o;
        }
    }
}

// ---------------------------------------------------------------------------
extern "C" void kernel_launch(void* const* d_in, const int* in_sizes, int n_in,
                              void* d_out, int out_size, void* d_ws, size_t ws_size,
                              hipStream_t stream) {
    const float* x       = (const float*)d_in[0];
    const float* w_qkv_c = (const float*)d_in[1];
    const float* w_qkv_s = (const float*)d_in[2];
    const float* w_proj  = (const float*)d_in[3];
    const float* b_proj  = (const float*)d_in[4];
    float* out = (float*)d_out;

    unsigned short* yh     = (unsigned short*)d_ws;               // R x 768 f16 (y)
    unsigned short* wqkv_h = yh + (size_t)R_ * KDIM;              // 768 x 768
    unsigned short* wp_h   = wqkv_h + (size_t)768 * 768;
    unsigned short* qkv_h  = wp_h + (size_t)768 * 768;            // R x 768 f16
    unsigned short* xc_h   = qkv_h + (size_t)R_ * NQKV_PAD;       // B*H*N*C*4 f16

    {
        const int total = (2 * 768 * 768) / 4;
        convert_weights<<<(total + 255) / 256, 256, 0, stream>>>(
            w_qkv_c, w_qkv_s, w_proj, wqkv_h, wp_h);
    }
    {
        const int mtiles = R_ / BM, ntiles = NQKV_PAD / BN;      // 147 x 6
        gemm_qkv_fused<<<mtiles * ntiles, 512, 0, stream>>>(
            x, wqkv_h, qkv_h, R_, NQKV_PAD, KDIM, ntiles);
    }
    chan_attn_xc<<<(B_ * H_ * N_) / 4, 256, 0, stream>>>(qkv_h, xc_h);
    spatial_attn_mfma<<<B_ * H_ * C_ * 2, 256, 0, stream>>>(qkv_h, xc_h, yh);
    {
        const int mtiles = R_ / 128, ntiles = D_ / 64;           // 147 x 12
        gemm_f16<<<mtiles * ntiles, 512, 0, stream>>>(
            yh, wp_h, b_proj, out, R_, D_, KDIM, ntiles);
    }
}

// Round 33
// 120.060 us; speedup vs baseline: 1.0128x; 1.0128x over previous
//
#include <hip/hip_runtime.h>
#include <math.h>

// Problem constants
#define B_  8
#define N_  196
#define C_  12
#define D_  768
#define H_  12
#define R_  (B_*N_*C_)      // 18816 rows
#define KDIM 768
#define NQKV_PAD 768        // 720 real qkv cols padded to 768

typedef _Float16 f16x8 __attribute__((ext_vector_type(8)));   // 8 f16 = 4 VGPR
typedef _Float16 f16x4 __attribute__((ext_vector_type(4)));   // 4 f16 = 2 VGPR
typedef __fp16 fp16x2 __attribute__((ext_vector_type(2)));    // cvt_pkrtz return type
typedef __attribute__((ext_vector_type(4))) float f32x4;

__device__ inline unsigned short f2h(float f) {
    union { _Float16 h; unsigned short u; } v; v.h = (_Float16)f; return v.u;
}
__device__ inline float h2f(unsigned short u) {
    union { unsigned short u; _Float16 h; } v; v.u = u; return (float)v.h;
}
// single-instruction packed f32x2 -> f16x2 (RTZ)
__device__ inline unsigned pk2u(float a, float b) {
    union { fp16x2 h; unsigned u; } v;
    v.h = __builtin_amdgcn_cvt_pkrtz(a, b);
    return v.u;
}
// scale both f16 halves of a packed word
__device__ inline unsigned scale2(unsigned u, float s) {
    return pk2u(h2f((unsigned short)(u & 0xffff)) * s,
                h2f((unsigned short)(u >> 16)) * s);
}

// ---------------------------------------------------------------------------
// Weights-only conversion (r27-verified).
// ---------------------------------------------------------------------------
__global__ __launch_bounds__(256) void convert_weights(
    const float* __restrict__ wc, const float* __restrict__ ws,
    const float* __restrict__ wp,
    unsigned short* __restrict__ wqkv_h, unsigned short* __restrict__ wp_h)
{
    int i = (blockIdx.x * 256 + threadIdx.x) * 4;
    float4 v; unsigned short* dh; int off;
    if (i < 768 * 768) {
        off = i;
        const int r = off / 768, k = off % 768;
        v = make_float4(0.f, 0.f, 0.f, 0.f);
        if (r < 144)      v = *reinterpret_cast<const float4*>(wc + r * 768 + k);
        else if (r < 720) v = *reinterpret_cast<const float4*>(ws + (r - 144) * 768 + k);
        dh = wqkv_h;
    } else {
        off = i - 768 * 768;
        if (off >= 768 * 768) return;
        v = *reinterpret_cast<const float4*>(wp + off);
        dh = wp_h;
    }
    uint2 h;
    h.x = pk2u(v.x, v.y);
    h.y = pk2u(v.z, v.w);
    *reinterpret_cast<uint2*>(dh + off) = h;
}

#define BM 128
#define BN 128
#define BK 64

__device__ inline void gload16(const unsigned short* src, void* ldsbase) {
    __builtin_amdgcn_global_load_lds(
        (const __attribute__((address_space(1))) unsigned int*)src,
        (__attribute__((address_space(3))) unsigned int*)ldsbase, 16, 0, 0);
}

// ---------------------------------------------------------------------------
// FUSED qkv GEMM (r30/r31-verified). Unchanged.
// ---------------------------------------------------------------------------
__global__ __launch_bounds__(512, 2) void gemm_qkv_fused(
    const float* __restrict__ Af, const unsigned short* __restrict__ Bh,
    unsigned short* __restrict__ outh, int M, int Nt, int K, int ntiles)
{
    __shared__ unsigned short sA[2][BM][BK];   // 2 x 16 KB
    __shared__ unsigned short sB[2][BN][BK];   // 2 x 16 KB

    const int nwg = gridDim.x;
    const int bid = blockIdx.x;
    const int xcd = bid & 7, slot = bid >> 3;
    const int q = nwg >> 3, r = nwg & 7;
    const int wg = (xcd < r ? xcd * (q + 1) : r * (q + 1) + (xcd - r) * q) + slot;
    const int mt = wg / ntiles, nt = wg - mt * ntiles;   // nt fast: A-panel reuse
    const int m0 = mt * BM, n0 = nt * BN;

    const int tid = threadIdx.x;
    const int w = tid >> 6, l = tid & 63;
    const int fl = l & 15, g = l >> 4;
    const int wr = (w >> 2) * 64;              // wave row base
    const int wc = (w & 3) * 32;               // wave col base

    f32x4 acc[4][2];
    #pragma unroll
    for (int i = 0; i < 4; ++i)
        #pragma unroll
        for (int j = 0; j < 2; ++j)
            acc[i][j] = (f32x4){0.f, 0.f, 0.f, 0.f};

    const int srow = w * 16 + (l >> 3);
    const int scol = ((l & 7) ^ (l >> 3)) * 8;

    float4 a0, a1, a2, a3;                     // A f32 staging regs (one k-tile)

#define LOADA(kk) {                                                                         \
    const float* paf = Af + (size_t)(m0 + srow) * K + (kk) + scol;                          \
    a0 = *reinterpret_cast<const float4*>(paf);                                             \
    a1 = *reinterpret_cast<const float4*>(paf + 4);                                         \
    a2 = *reinterpret_cast<const float4*>(paf + 8 * K);                                     \
    a3 = *reinterpret_cast<const float4*>(paf + 8 * K + 4); }

#define WRITEA(buf) {                                                                       \
    char* da = (char*)sA + (buf) * 16384 + w * 2048 + l * 16;                               \
    uint4 v0 = { pk2u(a0.x,a0.y), pk2u(a0.z,a0.w), pk2u(a1.x,a1.y), pk2u(a1.z,a1.w) };      \
    uint4 v1 = { pk2u(a2.x,a2.y), pk2u(a2.z,a2.w), pk2u(a3.x,a3.y), pk2u(a3.z,a3.w) };      \
    *reinterpret_cast<uint4*>(da) = v0;                                                     \
    *reinterpret_cast<uint4*>(da + 1024) = v1; }

#define STAGEB(buf, kk) {                                                                   \
    const unsigned short* pb = Bh + (size_t)(n0 + srow) * K + (kk) + scol;                  \
    char* db = (char*)sB + (buf) * 16384 + w * 2048;                                        \
    gload16(pb,          db);                                                               \
    gload16(pb + 8 * K,  db + 1024); }

    // prologue
    LOADA(0);                                  // 4 vm
    STAGEB(0, 0);                              // 2 vm
    asm volatile("s_waitcnt vmcnt(2)" ::: "memory");    // A(0) regs done (B(0) may fly)
    WRITEA(0);
    LOADA(BK);                                 // aregs(1), 4 vm
    asm volatile("s_waitcnt lgkmcnt(0)" ::: "memory");  // A(0) writes done

    const int KT = K / BK;             // 12
    int cur = 0;
    for (int t = 0; t < KT; ++t) {
        if (t + 1 < KT) {
            STAGEB(cur ^ 1, (t + 1) * BK);                     // 2 vm
            asm volatile("s_waitcnt vmcnt(2)" ::: "memory");   // B(t)+aregs(t+1) done
        } else {
            asm volatile("s_waitcnt vmcnt(0)" ::: "memory");
        }
        asm volatile("s_barrier" ::: "memory");                // buf[cur] ready

        // ---- ks = 0 ----
        {
            const int rcol = (g ^ (fl & 7)) * 8;
            f16x8 ah[4];
            #pragma unroll
            for (int fm = 0; fm < 4; ++fm)
                ah[fm] = *reinterpret_cast<const f16x8*>(&sA[cur][wr + fm * 16 + fl][rcol]);
            __builtin_amdgcn_s_setprio(1);
            #pragma unroll
            for (int fn = 0; fn < 2; ++fn) {
                const f16x8 bf = *reinterpret_cast<const f16x8*>(&sB[cur][wc + fn * 16 + fl][rcol]);
                #pragma unroll
                for (int fm = 0; fm < 4; ++fm)
                    acc[fm][fn] = __builtin_amdgcn_mfma_f32_16x16x32_f16(ah[fm], bf, acc[fm][fn], 0, 0, 0);
            }
            __builtin_amdgcn_s_setprio(0);
        }
        // A-path work under MFMA cover (published by end-of-iter lgkm+barrier)
        if (t + 1 < KT) WRITEA(cur ^ 1);
        if (t + 2 < KT) LOADA((t + 2) * BK);
        // ---- ks = 1 ----
        {
            const int rcol = ((4 + g) ^ (fl & 7)) * 8;
            f16x8 ah[4];
            #pragma unroll
            for (int fm = 0; fm < 4; ++fm)
                ah[fm] = *reinterpret_cast<const f16x8*>(&sA[cur][wr + fm * 16 + fl][rcol]);
            __builtin_amdgcn_s_setprio(1);
            #pragma unroll
            for (int fn = 0; fn < 2; ++fn) {
                const f16x8 bf = *reinterpret_cast<const f16x8*>(&sB[cur][wc + fn * 16 + fl][rcol]);
                #pragma unroll
                for (int fm = 0; fm < 4; ++fm)
                    acc[fm][fn] = __builtin_amdgcn_mfma_f32_16x16x32_f16(ah[fm], bf, acc[fm][fn], 0, 0, 0);
            }
            __builtin_amdgcn_s_setprio(0);
        }
        asm volatile("s_waitcnt lgkmcnt(0)" ::: "memory");  // publish A(t+1) writes
        asm volatile("s_barrier" ::: "memory");             // WAR fence
        cur ^= 1;
    }
#undef LOADA
#undef WRITEA
#undef STAGEB

    const int rg = g * 4;
    #pragma unroll
    for (int fm = 0; fm < 4; ++fm)
        #pragma unroll
        for (int fn = 0; fn < 2; ++fn) {
            const int row = m0 + wr + fm * 16 + rg;
            const int col = n0 + wc + fn * 16 + fl;
            #pragma unroll
            for (int rr = 0; rr < 4; ++rr)
                outh[(size_t)(row + rr) * Nt + col] = f2h(acc[fm][fn][rr]);
        }
}

// ---------------------------------------------------------------------------
// Proj GEMM: REVERTED to r30/r31-verified 128x128, 8 waves, setprio.
// ---------------------------------------------------------------------------
__global__ __launch_bounds__(512, 2) void gemm_f16(
    const unsigned short* __restrict__ Ah, const unsigned short* __restrict__ Bh,
    const float* __restrict__ bias,
    float* __restrict__ outp, int M, int Nt, int K, int ntiles)
{
    __shared__ unsigned short sA[2][BM][BK];   // 2 x 16 KB
    __shared__ unsigned short sB[2][BN][BK];   // 2 x 16 KB

    const int nwg = gridDim.x;
    const int bid = blockIdx.x;
    const int xcd = bid & 7, slot = bid >> 3;
    const int q = nwg >> 3, r = nwg & 7;
    const int wg = (xcd < r ? xcd * (q + 1) : r * (q + 1) + (xcd - r) * q) + slot;
    const int mt = wg / ntiles, nt = wg - mt * ntiles;
    const int m0 = mt * BM, n0 = nt * BN;

    const int tid = threadIdx.x;
    const int w = tid >> 6, l = tid & 63;
    const int fl = l & 15, g = l >> 4;
    const int wr = (w >> 2) * 64;
    const int wc = (w & 3) * 32;

    f32x4 acc[4][2];
    #pragma unroll
    for (int i = 0; i < 4; ++i)
        #pragma unroll
        for (int j = 0; j < 2; ++j)
            acc[i][j] = (f32x4){0.f, 0.f, 0.f, 0.f};

    const int srow = w * 16 + (l >> 3);
    const int scol = ((l & 7) ^ (l >> 3)) * 8;

#define STAGE(buf, kk) {                                                                    \
    const unsigned short* pa = Ah + (size_t)(m0 + srow) * K + (kk) + scol;                  \
    const unsigned short* pb = Bh + (size_t)(n0 + srow) * K + (kk) + scol;                  \
    char* da = (char*)sA + (buf) * 16384 + w * 2048;                                        \
    char* db = (char*)sB + (buf) * 16384 + w * 2048;                                        \
    gload16(pa,          da);                                                               \
    gload16(pa + 8 * K,  da + 1024);                                                        \
    gload16(pb,          db);                                                               \
    gload16(pb + 8 * K,  db + 1024); }

    STAGE(0, 0);

    const int KT = K / BK;             // 12
    int cur = 0;
    for (int t = 0; t < KT; ++t) {
        if (t + 1 < KT) {
            STAGE(cur ^ 1, (t + 1) * BK);
            asm volatile("s_waitcnt vmcnt(4)" ::: "memory");
        } else {
            asm volatile("s_waitcnt vmcnt(0)" ::: "memory");
        }
        asm volatile("s_barrier" ::: "memory");

        #pragma unroll
        for (int ks = 0; ks < 2; ++ks) {
            const int rcol = ((ks * 4 + g) ^ (fl & 7)) * 8;
            f16x8 ah[4];
            #pragma unroll
            for (int fm = 0; fm < 4; ++fm)
                ah[fm] = *reinterpret_cast<const f16x8*>(&sA[cur][wr + fm * 16 + fl][rcol]);
            __builtin_amdgcn_s_setprio(1);
            #pragma unroll
            for (int fn = 0; fn < 2; ++fn) {
                const f16x8 bf = *reinterpret_cast<const f16x8*>(&sB[cur][wc + fn * 16 + fl][rcol]);
                #pragma unroll
                for (int fm = 0; fm < 4; ++fm)
                    acc[fm][fn] = __builtin_amdgcn_mfma_f32_16x16x32_f16(ah[fm], bf, acc[fm][fn], 0, 0, 0);
            }
            __builtin_amdgcn_s_setprio(0);
        }
        asm volatile("s_barrier" ::: "memory");
        cur ^= 1;
    }
#undef STAGE

    const int rg = g * 4;
    #pragma unroll
    for (int fm = 0; fm < 4; ++fm)
        #pragma unroll
        for (int fn = 0; fn < 2; ++fn) {
            const int row = m0 + wr + fm * 16 + rg;
            const int col = n0 + wc + fn * 16 + fl;
            const float bv = bias[col];
            #pragma unroll
            for (int rr = 0; rr < 4; ++rr)
                outp[(size_t)(row + rr) * Nt + col] = acc[fm][fn][rr] + bv;
        }
}

// ---------------------------------------------------------------------------
// Channel attention -> xc ONLY (r31-verified). Unchanged.
// ---------------------------------------------------------------------------
__global__ __launch_bounds__(256) void chan_attn_xc(
    const unsigned short* __restrict__ qkv,
    unsigned short* __restrict__ xc)
{
    const int sub = threadIdx.x >> 6;
    const int t = threadIdx.x & 63;
    const int flat = blockIdx.x * 4 + sub;     // (b*12+h)*196 + n
    const int n = flat % 196;
    const int h = (flat / 196) % 12;
    const int b = flat / 2352;

    __shared__ float sQ[4][12][4], sK[4][12][4], sV[4][12][4];

    if (t < 36) {                              // (c, s) pairs: 12 x 3
        const int cc = t / 3, s = t % 3;
        const unsigned short* p =
            qkv + (size_t)((b * N_ + n) * 12 + cc) * NQKV_PAD + s * 48 + h * 4;
        const ushort4 v4 = *reinterpret_cast<const ushort4*>(p);
        float* dst = (s == 0) ? &sQ[sub][cc][0] : (s == 1) ? &sK[sub][cc][0] : &sV[sub][cc][0];
        dst[0] = h2f(v4.x); dst[1] = h2f(v4.y); dst[2] = h2f(v4.z); dst[3] = h2f(v4.w);
    }
    __syncthreads();

    if (t < 12) {
        const int c = t;
        float s[12];
        float m = -INFINITY;
        #pragma unroll
        for (int c2 = 0; c2 < 12; ++c2) {
            float d = 0.f;
            #pragma unroll
            for (int e = 0; e < 4; ++e) d += sQ[sub][c][e] * sK[sub][c2][e];
            s[c2] = d * 0.5f;
            m = fmaxf(m, s[c2]);
        }
        float lsum = 0.f;
        #pragma unroll
        for (int c2 = 0; c2 < 12; ++c2) { s[c2] = __expf(s[c2] - m); lsum += s[c2]; }
        const float inv = 1.f / lsum;
        float xcv[4];
        #pragma unroll
        for (int i = 0; i < 4; ++i) {
            float a = 0.f;
            #pragma unroll
            for (int c2 = 0; c2 < 12; ++c2) a += s[c2] * sV[sub][c2][i];
            xcv[i] = a * inv;
        }
        uint2 o;
        o.x = pk2u(xcv[0], xcv[1]);
        o.y = pk2u(xcv[2], xcv[3]);
        *reinterpret_cast<uint2*>(xc + (size_t)flat * 48 + c * 4) = o;
    }
}

// ---------------------------------------------------------------------------
// MFMA spatial attention + fused combine (r31/r32-verified, xc hoist kept).
// ---------------------------------------------------------------------------
__global__ __launch_bounds__(256) void spatial_attn_mfma(
    const unsigned short* __restrict__ qkv,
    const unsigned short* __restrict__ xc,
    unsigned short* __restrict__ y)
{
    __shared__ unsigned short Kl[224][24];
    __shared__ unsigned short Ql[208][24];
    __shared__ unsigned short Vt[16][236];

    const int bid2 = blockIdx.x;               // 2304 = 1152 x 2
    const int half = bid2 & 1;
    const int bid = bid2 >> 1;
    const int c = bid % 12;
    const int h = (bid / 12) % 12;
    const int b = bid / 144;
    const int tid = threadIdx.x;
    const int w = tid >> 6, l = tid & 63;
    const int fl = l & 15, g = l >> 4;
    const int qbase = half * 7;
    const int ntl = 7 - half;

    const float qs = 0.25f * 1.4426950408889634f;
    for (int idx = tid; idx < N_ * 2; idx += 256) {
        const int n = idx >> 1, eh = (idx & 1) * 8;   // 8 f16 per load
        const unsigned short* base =
            qkv + (size_t)((b * N_ + n) * 12 + c) * NQKV_PAD + 144 + h * 16 + eh;
        const uint4 q4 = *reinterpret_cast<const uint4*>(base);
        const uint4 k4 = *reinterpret_cast<const uint4*>(base + 192);
        const uint4 v4 = *reinterpret_cast<const uint4*>(base + 384);
        uint4 qsc;
        qsc.x = scale2(q4.x, qs); qsc.y = scale2(q4.y, qs);
        qsc.z = scale2(q4.z, qs); qsc.w = scale2(q4.w, qs);
        *reinterpret_cast<uint4*>(&Ql[n][eh]) = qsc;
        *reinterpret_cast<uint4*>(&Kl[n][eh]) = k4;
        Vt[eh + 0][n] = (unsigned short)(v4.x & 0xffff);
        Vt[eh + 1][n] = (unsigned short)(v4.x >> 16);
        Vt[eh + 2][n] = (unsigned short)(v4.y & 0xffff);
        Vt[eh + 3][n] = (unsigned short)(v4.y >> 16);
        Vt[eh + 4][n] = (unsigned short)(v4.z & 0xffff);
        Vt[eh + 5][n] = (unsigned short)(v4.z >> 16);
        Vt[eh + 6][n] = (unsigned short)(v4.w & 0xffff);
        Vt[eh + 7][n] = (unsigned short)(v4.w >> 16);
    }
    for (int idx = tid; idx < 16 * 28; idx += 256) {
        const int d = idx / 28, n = 196 + idx % 28;
        Vt[d][n] = 0;
    }
    __syncthreads();

    f32x4 accO[2];
    float lsum[2];
    #pragma unroll
    for (int j = 0; j < 2; ++j) {
        accO[j] = (f32x4){0.f, 0.f, 0.f, 0.f};
        lsum[j] = 0.f;
    }
    const f32x4 zf = (f32x4){0.f, 0.f, 0.f, 0.f};

    f16x4 Bq[2];
    float xv[2][4];                            // hoisted xc prefetch
    #pragma unroll
    for (int j = 0; j < 2; ++j) {
        const int qtl = w + 4 * j;
        const int qt = (qtl < ntl) ? (qbase + qtl) : 12;
        Bq[j] = *reinterpret_cast<const f16x4*>(&Ql[qt * 16 + fl][4 * g]);
        int n = qt * 16 + fl; if (n > 195) n = 195;
        const ushort4 xc4 = *reinterpret_cast<const ushort4*>(
            xc + (size_t)((b * 12 + h) * 196 + n) * 48 + c * 4);
        xv[j][0] = h2f(xc4.x); xv[j][1] = h2f(xc4.y);
        xv[j][2] = h2f(xc4.z); xv[j][3] = h2f(xc4.w);
    }

    for (int ch = 0; ch < 7; ++ch) {
        const int kb0 = ch * 32;
        const f16x4 Ak0 = *reinterpret_cast<const f16x4*>(&Kl[kb0 + fl][4 * g]);
        const f16x4 Ak1 = *reinterpret_cast<const f16x4*>(&Kl[kb0 + 16 + fl][4 * g]);
        const f16x4 Av0 = *reinterpret_cast<const f16x4*>(&Vt[fl][kb0 + 4 * g]);
        const f16x4 Av1 = *reinterpret_cast<const f16x4*>(&Vt[fl][kb0 + 16 + 4 * g]);

        #pragma unroll
        for (int j = 0; j < 2; ++j) {
            if (w + 4 * j >= ntl) continue;

            __builtin_amdgcn_s_setprio(1);
            f32x4 T0 = __builtin_amdgcn_mfma_f32_16x16x16f16(Ak0, Bq[j], zf, 0, 0, 0);
            f32x4 T1 = __builtin_amdgcn_mfma_f32_16x16x16f16(Ak1, Bq[j], zf, 0, 0, 0);
            __builtin_amdgcn_s_setprio(0);

            float s0 = T0[0], s1 = T0[1], s2 = T0[2], s3 = T0[3];
            float s4 = T1[0], s5 = T1[1], s6 = T1[2], s7 = T1[3];
            if (ch == 6) {
                const int kg = kb0 + 4 * g;
                if (kg + 0 >= 196) s0 = -1e30f;
                if (kg + 1 >= 196) s1 = -1e30f;
                if (kg + 2 >= 196) s2 = -1e30f;
                if (kg + 3 >= 196) s3 = -1e30f;
                s4 = -1e30f; s5 = -1e30f; s6 = -1e30f; s7 = -1e30f;
            }
            const float p0 = exp2f(s0), p1 = exp2f(s1);
            const float p2 = exp2f(s2), p3 = exp2f(s3);
            const float p4 = exp2f(s4), p5 = exp2f(s5);
            const float p6 = exp2f(s6), p7 = exp2f(s7);
            lsum[j] += ((p0 + p1) + (p2 + p3)) + ((p4 + p5) + (p6 + p7));

            union { unsigned u[2]; f16x4 v; } pa, pb;
            pa.u[0] = pk2u(p0, p1); pa.u[1] = pk2u(p2, p3);
            pb.u[0] = pk2u(p4, p5); pb.u[1] = pk2u(p6, p7);

            __builtin_amdgcn_s_setprio(1);
            accO[j] = __builtin_amdgcn_mfma_f32_16x16x16f16(Av0, pa.v, accO[j], 0, 0, 0);
            accO[j] = __builtin_amdgcn_mfma_f32_16x16x16f16(Av1, pb.v, accO[j], 0, 0, 0);
            __builtin_amdgcn_s_setprio(0);
        }
    }

    #pragma unroll
    for (int j = 0; j < 2; ++j) {
        const int qtl = w + 4 * j;
        if (qtl >= ntl) continue;
        const int qt = qbase + qtl;
        float ls = lsum[j];
        ls += __shfl_xor(ls, 16);
        ls += __shfl_xor(ls, 32);
        const int n = qt * 16 + fl;
        if (n < 196) {
            const float inv = 1.f / ls;
            const float o0 = accO[j][0] * inv, o1 = accO[j][1] * inv;
            const float o2 = accO[j][2] * inv, o3 = accO[j][3] * inv;
            const float x0 = xv[j][0], x1 = xv[j][1];
            const float x2 = xv[j][2], x3 = xv[j][3];
            unsigned short* yrow =
                y + ((size_t)(b * N_ + n) * 12 + h) * (size_t)D_ + c * 64 + 4 * g;
            uint2 o;
            o.x = pk2u(x0 * o0, x0 * o1); o.y = pk2u(x0 * o2, x0 * o3);
            *reinterpret_cast<uint2*>(yrow) = o;
            o.x = pk2u(x1 * o0, x1 * o1); o.y = pk2u(x1 * o2, x1 * o3);
            *reinterpret_cast<uint2*>(yrow + 16) = o;
            o.x = pk2u(x2 * o0, x2 * o1); o.y = pk2u(x2 * o2, x2 * o3);
            *reinterpret_cast<uint2*>(yrow + 32) = o;
            o.x = pk2u(x3 * o0, x3 * o1); o.y = pk2u(x3 * o2, x3 * o3);
            *reinterpret_cast<uint2*>(yrow + 48) = o;
        }
    }
}

// ---------------------------------------------------------------------------
extern "C" void kernel_launch(void* const* d_in, const int* in_sizes, int n_in,
                              void* d_out, int out_size, void* d_ws, size_t ws_size,
                              hipStream_t stream) {
    const float* x       = (const float*)d_in[0];
    const float* w_qkv_c = (const float*)d_in[1];
    const float* w_qkv_s = (const float*)d_in[2];
    const float* w_proj  = (const float*)d_in[3];
    const float* b_proj  = (const float*)d_in[4];
    float* out = (float*)d_out;

    unsigned short* yh     = (unsigned short*)d_ws;               // R x 768 f16 (y)
    unsigned short* wqkv_h = yh + (size_t)R_ * KDIM;              // 768 x 768
    unsigned short* wp_h   = wqkv_h + (size_t)768 * 768;
    unsigned short* qkv_h  = wp_h + (size_t)768 * 768;            // R x 768 f16
    unsigned short* xc_h   = qkv_h + (size_t)R_ * NQKV_PAD;       // B*H*N*C*4 f16

    {
        const int total = (2 * 768 * 768) / 4;
        convert_weights<<<(total + 255) / 256, 256, 0, stream>>>(
            w_qkv_c, w_qkv_s, w_proj, wqkv_h, wp_h);
    }
    {
        const int mtiles = R_ / BM, ntiles = NQKV_PAD / BN;      // 147 x 6
        gemm_qkv_fused<<<mtiles * ntiles, 512, 0, stream>>>(
            x, wqkv_h, qkv_h, R_, NQKV_PAD, KDIM, ntiles);
    }
    chan_attn_xc<<<(B_ * H_ * N_) / 4, 256, 0, stream>>>(qkv_h, xc_h);
    spatial_attn_mfma<<<B_ * H_ * C_ * 2, 256, 0, stream>>>(qkv_h, xc_h, yh);
    {
        const int mtiles = R_ / BM, ntiles = D_ / BN;            // 147 x 6
        gemm_f16<<<mtiles * ntiles, 512, 0, stream>>>(
            yh, wp_h, b_proj, out, R_, D_, KDIM, ntiles);
    }
}